// Round 4
// baseline (586.248 us; speedup 1.0000x reference)
//
#include <hip/hip_runtime.h>

// ---------------------------------------------------------------------------
// SAGE-GCN LSTM, N=1024, J=24, D=64.  R4 = R3 + de-spill + conflict-free Bf:
//  mono: 256 blocks (1/CU) x 512 thr (8 waves), all 24 cells in-kernel.
//   GEMM per step: pre^T[256 x 96] = Wcat^T[256x256] @ v^T[256x96]
//   A = W in VGPRs (gate-interleaved M so epilogue is lane-local),
//   B = v built in LDS fragment layout. W_M=4: each vfrag feeds 2 MFMAs.
//   __launch_bounds__(512, 2): 256-VGPR cap -> W tiles stay resident (R3
//   spilled at 128 cap: 674 MB scratch fetch).
//   v-build lanes remapped Mrow-fastest -> conflict-free ds_write_b128.
//  dec: MFMA, 4-wave K-split + LDS reduce.
// ---------------------------------------------------------------------------

typedef __bf16 bf16x8 __attribute__((ext_vector_type(8)));
typedef float f32x16 __attribute__((ext_vector_type(16)));

__constant__ int c_nbr[24][5] = {
  {0,1,2,3,-1},  {1,0,4,-1,-1}, {2,0,5,-1,-1}, {3,0,6,-1,-1},
  {4,1,7,-1,-1}, {5,2,8,-1,-1}, {6,3,9,-1,-1}, {7,4,10,-1,-1},
  {8,5,11,-1,-1},{9,6,12,13,14},{10,7,-1,-1,-1},{11,8,-1,-1,-1},
  {12,9,15,-1,-1},{13,9,16,-1,-1},{14,9,17,-1,-1},{15,12,-1,-1,-1},
  {16,13,18,-1,-1},{17,14,19,-1,-1},{18,16,20,-1,-1},{19,17,21,-1,-1},
  {20,18,22,-1,-1},{21,19,23,-1,-1},{22,20,-1,-1,-1},{23,21,-1,-1,-1}
};
__constant__ float c_invdeg[24] = {
  0.25f, 1.f/3.f, 1.f/3.f, 1.f/3.f, 1.f/3.f, 1.f/3.f, 1.f/3.f, 1.f/3.f,
  1.f/3.f, 0.2f, 0.5f, 0.5f, 1.f/3.f, 1.f/3.f, 1.f/3.f, 0.5f,
  1.f/3.f, 1.f/3.f, 1.f/3.f, 1.f/3.f, 1.f/3.f, 1.f/3.f, 0.5f, 0.5f
};

__device__ __forceinline__ unsigned short f2b(float f) {   // fp32->bf16 RNE
  unsigned int u = __float_as_uint(f);
  u += 0x7fffu + ((u >> 16) & 1u);
  return (unsigned short)(u >> 16);
}
__device__ __forceinline__ unsigned pk2(float a, float b) {
  return (unsigned)f2b(a) | ((unsigned)f2b(b) << 16);
}
__device__ __forceinline__ float b2f_lo(unsigned u) { return __uint_as_float(u << 16); }
__device__ __forceinline__ float b2f_hi(unsigned u) { return __uint_as_float(u & 0xffff0000u); }
__device__ __forceinline__ float sigm_(float x) { return 1.0f / (1.0f + __expf(-x)); }
__device__ __forceinline__ float tanh_(float x) { return 2.0f / (1.0f + __expf(-2.0f * x)) - 1.0f; }

// ---------------------------------------------------------------------------
// prep: Wfrag = A-operand frag layout (gate-interleaved M), biasv, dec B-frags.
//  m32 (col within M-tile mt): gate g = m32&3, d = mt*8 + (m32>>2)
//  k = t*16 + (lane>>5)*8 + i; q=k>>6: q0 Wl[2g], q1 Wr[2g], q2 Wl[2g+1], q3 Wr[2g+1]
// ---------------------------------------------------------------------------
__global__ void prep3_kernel(const float* __restrict__ sWl, const float* __restrict__ sbl,
                             const float* __restrict__ sWr, const float* __restrict__ gb,
                             const float* __restrict__ dW,
                             unsigned short* __restrict__ Wfrag,
                             float* __restrict__ biasv,
                             unsigned short* __restrict__ Bdec)
{
  int id = blockIdx.x * 256 + threadIdx.x;          // 213248 total
  if (id < 65536) {                                  // Wfrag [mt][t][lane][8]
    int i = id & 7, l = (id >> 3) & 63, t = (id >> 9) & 15, mt = id >> 13;
    int m32 = l & 31;
    int g = m32 & 3, d = mt * 8 + (m32 >> 2);
    int k = t * 16 + ((l >> 5) << 3) + i;
    int q = k >> 6, kk = k & 63;
    const float* Ws = (q & 1) ? sWr : sWl;
    Wfrag[id] = f2b(Ws[((2 * g + (q >> 1)) * 64 + kk) * 64 + d]);
  } else if (id < 65792) {                           // biasv[mt*32 + m32]
    int c = id - 65536;
    int mt = c >> 5, m32 = c & 31;
    int g = m32 & 3, d = mt * 8 + (m32 >> 2);
    biasv[c] = sbl[(2 * g) * 64 + d] + sbl[(2 * g + 1) * 64 + d] + gb[g * 64 + d];
  } else {                                           // Bdec [nt][96 t][lane][8]
    int p = id - 65792;                              // < 147456
    int i = p & 7, l = (p >> 3) & 63;
    int rem = p >> 9;                                // nt*96 + t
    int nt = rem / 96, t = rem - nt * 96;
    int e = nt * 32 + (l & 31);
    int k = t * 16 + ((l >> 5) << 3) + i;
    Bdec[p] = (e < 72) ? f2b(dW[k * 72 + e]) : (unsigned short)0;
  }
}

// ---------------------------------------------------------------------------
// mono: all 24 cells for 4 batch elements per block.
// ---------------------------------------------------------------------------
__global__ __launch_bounds__(512, 2) void mono3_kernel(
    const float* __restrict__ src, const float* __restrict__ tgt,
    const float* __restrict__ encW, const float* __restrict__ encb,
    const float* __restrict__ gw,
    const unsigned short* __restrict__ Wfrag,
    const float* __restrict__ biasv,
    unsigned short* __restrict__ obuf)
{
  __shared__ __align__(16) unsigned short Bf[3 * 16 * 64 * 8];  // 48 KB v-frags
  __shared__ __align__(16) unsigned short xs[96 * 64];          // 12 KB (swizzled)
  __shared__ __align__(16) unsigned short hs[96 * 64];          // 12 KB (swizzled)

  const int tid = threadIdx.x;
  const int n4 = blockIdx.x * 4;
  const int w = tid >> 6, l = tid & 63;
  const int wm = w & 3, wnt = w >> 2;
  const int l31 = l & 31, hi = l >> 5;

  // ---- persistent W: 2 M-tiles x 16 k-steps = 128 VGPR -------------------
  bf16x8 W0[16], W1[16];
  {
    const bf16x8* p0 = reinterpret_cast<const bf16x8*>(Wfrag) + ((2 * wm) * 16) * 64 + l;
    const bf16x8* p1 = reinterpret_cast<const bf16x8*>(Wfrag) + ((2 * wm + 1) * 16) * 64 + l;
    #pragma unroll
    for (int t = 0; t < 16; ++t) { W0[t] = p0[t * 64]; W1[t] = p1[t * 64]; }
  }
  // ---- bias (bf16-packed, per acc-reg pair) ------------------------------
  unsigned bias_u[2][8];
  #pragma unroll
  for (int mtl = 0; mtl < 2; ++mtl) {
    #pragma unroll
    for (int p = 0; p < 8; ++p) {
      int r0 = 2 * p, r1 = 2 * p + 1;
      int m0 = (r0 & 3) + 8 * (r0 >> 2) + 4 * hi;
      int m1 = (r1 & 3) + 8 * (r1 >> 2) + 4 * hi;
      bias_u[mtl][p] = pk2(biasv[(2 * wm + mtl) * 32 + m0], biasv[(2 * wm + mtl) * 32 + m1]);
    }
  }
  // ---- gate_w (bf16-packed per (gate,u): lo=mtl0, hi=mtl1) ---------------
  unsigned gw_u[3][4];
  #pragma unroll
  for (int g = 0; g < 3; ++g) {
    #pragma unroll
    for (int u = 0; u < 4; ++u) {
      int d0 = (2 * wm) * 8 + 2 * u + hi;
      gw_u[g][u] = pk2(gw[g * 64 + d0], gw[g * 64 + d0 + 8]);
    }
  }

  float creg[16];
  #pragma unroll
  for (int i = 0; i < 16; ++i) creg[i] = 0.0f;

  // zero h state
  for (int i = tid; i < 3072; i += 512) reinterpret_cast<unsigned*>(hs)[i] = 0u;

  auto enc_to_xs = [&](const float* base, int stride) {
    #pragma unroll
    for (int ii = 0; ii < 12; ++ii) {
      int idx = tid + ii * 512;                 // < 6144
      int ns = idx / 1536;
      int r2 = idx - ns * 1536;
      int jj = r2 >> 6, dd = r2 & 63;
      const float* f = base + (size_t)ns * stride + jj * 3;
      float v = encb[dd] + f[0] * encW[dd] + f[1] * encW[64 + dd] + f[2] * encW[128 + dd];
      int row = ns * 24 + jj;
      xs[row * 64 + (((dd >> 3) ^ (row & 7)) << 3) + (dd & 7)] = f2b(fmaxf(v, 0.0f));
    }
  };

  enc_to_xs(src + ((size_t)n4 * 16 + 4) * 72, 16 * 72);   // warm-up frame 4
  __syncthreads();

  #pragma unroll 1
  for (int step = 0; step < 24; ++step) {
    if (step == 12) {                          // decode init: re-encode tgt[:,0]
      enc_to_xs(tgt + (size_t)n4 * 12 * 72, 12 * 72);
      __syncthreads();
    }

    // ---- v-build: B-fragments [nt][t][lane][8] ---------------------------
    // job -> (Mrow fastest, ch per 32 lanes): write idx16%8 = Mrow%8 distinct
    // across each 8-lane group -> conflict-free b128 writes.
    #pragma unroll
    for (int it = 0; it < 3; ++it) {           // agg sections q0 (x), q2 (h)
      int job = tid + it * 512;                // < 1536
      int sec = (job >= 768) ? 1 : 0;
      int rem = job - sec * 768;
      int u8 = rem >> 8, r8 = rem & 255;
      int Mrow = u8 * 32 + (r8 & 31), ch = r8 >> 5;
      const unsigned short* sb = sec ? hs : xs;
      int ns = (Mrow * 2731) >> 16;
      int jj = Mrow - ns * 24;
      float s0 = 0, s1 = 0, s2 = 0, s3 = 0, s4 = 0, s5 = 0, s6 = 0, s7 = 0;
      #pragma unroll
      for (int m = 0; m < 5; ++m) {
        int nb = c_nbr[jj][m];
        if (nb >= 0) {
          int nr = ns * 24 + nb;
          uint4 u = *reinterpret_cast<const uint4*>(sb + nr * 64 + ((ch ^ (nr & 7)) << 3));
          s0 += b2f_lo(u.x); s1 += b2f_hi(u.x);
          s2 += b2f_lo(u.y); s3 += b2f_hi(u.y);
          s4 += b2f_lo(u.z); s5 += b2f_hi(u.z);
          s6 += b2f_lo(u.w); s7 += b2f_hi(u.w);
        }
      }
      float sc = c_invdeg[jj];
      uint4 o;
      o.x = pk2(s0 * sc, s1 * sc); o.y = pk2(s2 * sc, s3 * sc);
      o.z = pk2(s4 * sc, s5 * sc); o.w = pk2(s6 * sc, s7 * sc);
      int kb = sec * 128 + ch * 8;
      int t = kb >> 4, h2 = ch & 1;
      *reinterpret_cast<uint4*>(Bf + ((((Mrow >> 5) * 16 + t) * 64) + (Mrow & 31) + (h2 << 5)) * 8) = o;
    }
    #pragma unroll
    for (int it = 0; it < 3; ++it) {           // copy sections q1 (x), q3 (h)
      int job = tid + it * 512;
      int sec = (job >= 768) ? 1 : 0;
      int rem = job - sec * 768;
      int u8 = rem >> 8, r8 = rem & 255;
      int Mrow = u8 * 32 + (r8 & 31), ch = r8 >> 5;
      const unsigned short* sb = sec ? hs : xs;
      uint4 u = *reinterpret_cast<const uint4*>(sb + Mrow * 64 + ((ch ^ (Mrow & 7)) << 3));
      int kb = 64 + sec * 128 + ch * 8;
      int t = kb >> 4, h2 = ch & 1;
      *reinterpret_cast<uint4*>(Bf + ((((Mrow >> 5) * 16 + t) * 64) + (Mrow & 31) + (h2 << 5)) * 8) = u;
    }
    __syncthreads();

    // ---- GEMM + lane-local epilogue --------------------------------------
#define EPI_HALF(NT, CB, A, MTL)                                               \
    {                                                                          \
      const int mt = 2 * wm + (MTL);                                           \
      int row = (NT) * 32 + l31;                                               \
      int ns = (row * 2731) >> 16;                                             \
      int jj = row - ns * 24;                                                  \
      _Pragma("unroll")                                                        \
      for (int u = 0; u < 4; ++u) {                                            \
        float cv = creg[(CB) + (MTL) * 4 + u];                                 \
        float g0 = (MTL) ? b2f_hi(gw_u[0][u]) : b2f_lo(gw_u[0][u]);            \
        float g1 = (MTL) ? b2f_hi(gw_u[1][u]) : b2f_lo(gw_u[1][u]);            \
        float g2 = (MTL) ? b2f_hi(gw_u[2][u]) : b2f_lo(gw_u[2][u]);            \
        float I = sigm_(A[4 * u + 0] + g0 * cv);                               \
        float F = sigm_(A[4 * u + 1] + g1 * cv);                               \
        float T = tanh_(A[4 * u + 2]);                                         \
        float cn = F * cv + I * T;                                             \
        float O = sigm_(A[4 * u + 3] + g2 * cn);                               \
        float h = O * tanh_(cn);                                               \
        creg[(CB) + (MTL) * 4 + u] = cn;                                       \
        int d7 = 2 * u + hi;                                                   \
        int off = row * 64 + ((mt ^ (row & 7)) << 3) + d7;                     \
        xs[off] = f2b(O);                                                      \
        hs[off] = f2b(h);                                                      \
        if (step >= 12)                                                        \
          obuf[((size_t)((n4 + ns) * 12 + (step - 12))) * 1536 + jj * 64 + mt * 8 + d7] = f2b(O); \
      }                                                                        \
    }

#define ROUND(NT, CB)                                                          \
    {                                                                          \
      f32x16 a0, a1;                                                           \
      _Pragma("unroll")                                                        \
      for (int p = 0; p < 8; ++p) {                                            \
        a0[2 * p] = b2f_lo(bias_u[0][p]); a0[2 * p + 1] = b2f_hi(bias_u[0][p]);\
        a1[2 * p] = b2f_lo(bias_u[1][p]); a1[2 * p + 1] = b2f_hi(bias_u[1][p]);\
      }                                                                        \
      _Pragma("unroll")                                                        \
      for (int t = 0; t < 16; ++t) {                                           \
        bf16x8 vf = *reinterpret_cast<const bf16x8*>(Bf + (((NT) * 16 + t) * 64 + l) * 8); \
        a0 = __builtin_amdgcn_mfma_f32_32x32x16_bf16(W0[t], vf, a0, 0, 0, 0);  \
        a1 = __builtin_amdgcn_mfma_f32_32x32x16_bf16(W1[t], vf, a1, 0, 0, 0);  \
      }                                                                        \
      EPI_HALF(NT, CB, a0, 0)                                                  \
      EPI_HALF(NT, CB, a1, 1)                                                  \
    }

    if (wnt == 0) { ROUND(0, 0) ROUND(1, 8) }
    else          { ROUND(2, 0) }
#undef ROUND
#undef EPI_HALF
    __syncthreads();
  }
}

// ---------------------------------------------------------------------------
// dec: out[row][e] = O[row,:] . decW[:,e] + db[e]; rows = n*12+ts.
// block: 32 rows, 4 waves K-split (384 each), 3 col-tiles, LDS reduce.
// ---------------------------------------------------------------------------
__global__ __launch_bounds__(256) void dec3_kernel(
    const unsigned short* __restrict__ obuf,
    const unsigned short* __restrict__ Bdec,
    const float* __restrict__ db,
    float* __restrict__ out)
{
  __shared__ float part[4 * 3 * 64 * 16];    // 48 KB
  const int tid = threadIdx.x;
  const int w = tid >> 6, l = tid & 63;
  const int l31 = l & 31, hi = l >> 5;
  const int r0 = blockIdx.x * 32;

  f32x16 a0, a1, a2;
  #pragma unroll
  for (int r = 0; r < 16; ++r) { a0[r] = 0.f; a1[r] = 0.f; a2[r] = 0.f; }

  const unsigned short* Ap = obuf + (size_t)(r0 + l31) * 1536 + hi * 8;
  #pragma unroll 4
  for (int tt = 0; tt < 24; ++tt) {
    int kt = w * 24 + tt;
    bf16x8 av = *reinterpret_cast<const bf16x8*>(Ap + kt * 16);
    bf16x8 b0 = *reinterpret_cast<const bf16x8*>(Bdec + ((0 * 96 + kt) * 64 + l) * 8);
    bf16x8 b1 = *reinterpret_cast<const bf16x8*>(Bdec + ((1 * 96 + kt) * 64 + l) * 8);
    bf16x8 b2 = *reinterpret_cast<const bf16x8*>(Bdec + ((2 * 96 + kt) * 64 + l) * 8);
    a0 = __builtin_amdgcn_mfma_f32_32x32x16_bf16(av, b0, a0, 0, 0, 0);
    a1 = __builtin_amdgcn_mfma_f32_32x32x16_bf16(av, b1, a1, 0, 0, 0);
    a2 = __builtin_amdgcn_mfma_f32_32x32x16_bf16(av, b2, a2, 0, 0, 0);
  }
  #pragma unroll
  for (int r = 0; r < 16; ++r) {
    part[((w * 3 + 0) * 64 + l) * 16 + r] = a0[r];
    part[((w * 3 + 1) * 64 + l) * 16 + r] = a1[r];
    part[((w * 3 + 2) * 64 + l) * 16 + r] = a2[r];
  }
  __syncthreads();

  // reduce 4 K-partials; thread -> (row = tid>>3, e = (tid&7)*12 + 0..11)
  int row = tid >> 3;
  int hi2 = (row >> 2) & 1;
  int rr = 4 * (row >> 3) + (row & 3);
  #pragma unroll
  for (int ei = 0; ei < 12; ++ei) {
    int e = (tid & 7) * 12 + ei;
    if (e < 72) {
      int nt = e >> 5, e32 = e & 31;
      float s = db[e];
      #pragma unroll
      for (int w2 = 0; w2 < 4; ++w2)
        s += part[((w2 * 3 + nt) * 64 + e32 + 32 * hi2) * 16 + rr];
      out[(size_t)(r0 + row) * 72 + e] = s;
    }
  }
}

// ---------------------------------------------------------------------------
extern "C" void kernel_launch(void* const* d_in, const int* in_sizes, int n_in,
                              void* d_out, int out_size, void* d_ws, size_t ws_size,
                              hipStream_t stream) {
  const float* src  = (const float*)d_in[0];   // [1024,16,72]
  const float* tgt  = (const float*)d_in[1];   // [1024,12,72]
  const float* encW = (const float*)d_in[2];   // [3,64]
  const float* encb = (const float*)d_in[3];   // [64]
  const float* sWl  = (const float*)d_in[4];   // [8,64,64]
  const float* sbl  = (const float*)d_in[5];   // [8,64]
  const float* sWr  = (const float*)d_in[6];   // [8,64,64]
  const float* gw   = (const float*)d_in[7];   // [3,1,64]
  const float* gb   = (const float*)d_in[8];   // [4,1,64]
  const float* dW   = (const float*)d_in[9];   // [1536,72]
  const float* db   = (const float*)d_in[10];  // [72]
  float* out = (float*)d_out;

  unsigned short* obuf  = (unsigned short*)d_ws;        // 12288*1536 bf16
  unsigned short* Wfrag = obuf + (size_t)12288 * 1536;  // 65536 bf16
  unsigned short* Bdec  = Wfrag + 65536;                // 147456 bf16
  float*          biasv = (float*)(Bdec + 147456);      // 256 f32

  prep3_kernel<<<833, 256, 0, stream>>>(sWl, sbl, sWr, gb, dW, Wfrag, biasv, Bdec);
  mono3_kernel<<<256, 512, 0, stream>>>(src, tgt, encW, encb, gw, Wfrag, biasv, obuf);
  dec3_kernel<<<384, 256, 0, stream>>>(obuf, Bdec, db, out);
}

// Round 5
// 246.023 us; speedup vs baseline: 2.3829x; 2.3829x over previous
//
#include <hip/hip_runtime.h>

// ---------------------------------------------------------------------------
// SAGE-GCN LSTM, N=1024, J=24, D=64.  R5 = WM=8 de-spill restructure:
//  mono: 256 blocks (1/CU) x 512 thr (8 waves), all 24 cells in-kernel.
//   GEMM per step: pre^T[256 x 96] = Wcat^T[256x256] @ v^T[256x96]
//   Each wave owns ONE M-tile mt=w (64 W-VGPRs, fits the 128 arch cap that
//   spilled R3/R4's 128-reg W) and all 3 N-tiles: 48 MFMAs, 3 acc chains.
//   B = v built in LDS fragment layout (conflict-free writes, R4 remap).
//   Epilogue fully lane-local (gate-interleaved M), c-state fp32 in regs.
//  dec: MFMA, 4-wave K-split + LDS reduce.  prep: weight packing.
// ---------------------------------------------------------------------------

typedef __bf16 bf16x8 __attribute__((ext_vector_type(8)));
typedef float f32x16 __attribute__((ext_vector_type(16)));

__constant__ int c_nbr[24][5] = {
  {0,1,2,3,-1},  {1,0,4,-1,-1}, {2,0,5,-1,-1}, {3,0,6,-1,-1},
  {4,1,7,-1,-1}, {5,2,8,-1,-1}, {6,3,9,-1,-1}, {7,4,10,-1,-1},
  {8,5,11,-1,-1},{9,6,12,13,14},{10,7,-1,-1,-1},{11,8,-1,-1,-1},
  {12,9,15,-1,-1},{13,9,16,-1,-1},{14,9,17,-1,-1},{15,12,-1,-1,-1},
  {16,13,18,-1,-1},{17,14,19,-1,-1},{18,16,20,-1,-1},{19,17,21,-1,-1},
  {20,18,22,-1,-1},{21,19,23,-1,-1},{22,20,-1,-1,-1},{23,21,-1,-1,-1}
};
__constant__ float c_invdeg[24] = {
  0.25f, 1.f/3.f, 1.f/3.f, 1.f/3.f, 1.f/3.f, 1.f/3.f, 1.f/3.f, 1.f/3.f,
  1.f/3.f, 0.2f, 0.5f, 0.5f, 1.f/3.f, 1.f/3.f, 1.f/3.f, 0.5f,
  1.f/3.f, 1.f/3.f, 1.f/3.f, 1.f/3.f, 1.f/3.f, 1.f/3.f, 0.5f, 0.5f
};

__device__ __forceinline__ unsigned short f2b(float f) {   // fp32->bf16 RNE
  unsigned int u = __float_as_uint(f);
  u += 0x7fffu + ((u >> 16) & 1u);
  return (unsigned short)(u >> 16);
}
__device__ __forceinline__ unsigned pk2(float a, float b) {
  return (unsigned)f2b(a) | ((unsigned)f2b(b) << 16);
}
__device__ __forceinline__ float b2f_lo(unsigned u) { return __uint_as_float(u << 16); }
__device__ __forceinline__ float b2f_hi(unsigned u) { return __uint_as_float(u & 0xffff0000u); }
__device__ __forceinline__ float sigm_(float x) { return 1.0f / (1.0f + __expf(-x)); }
__device__ __forceinline__ float tanh_(float x) { return 2.0f / (1.0f + __expf(-2.0f * x)) - 1.0f; }

// ---------------------------------------------------------------------------
// prep: Wfrag = A-operand frag layout (gate-interleaved M), biasv, dec B-frags.
//  m32 (col within M-tile mt): gate g = m32&3, d = mt*8 + (m32>>2)
//  k = t*16 + (lane>>5)*8 + i; q=k>>6: q0 Wl[2g], q1 Wr[2g], q2 Wl[2g+1], q3 Wr[2g+1]
// ---------------------------------------------------------------------------
__global__ void prep3_kernel(const float* __restrict__ sWl, const float* __restrict__ sbl,
                             const float* __restrict__ sWr, const float* __restrict__ gb,
                             const float* __restrict__ dW,
                             unsigned short* __restrict__ Wfrag,
                             float* __restrict__ biasv,
                             unsigned short* __restrict__ Bdec)
{
  int id = blockIdx.x * 256 + threadIdx.x;          // 213248 total
  if (id < 65536) {                                  // Wfrag [mt][t][lane][8]
    int i = id & 7, l = (id >> 3) & 63, t = (id >> 9) & 15, mt = id >> 13;
    int m32 = l & 31;
    int g = m32 & 3, d = mt * 8 + (m32 >> 2);
    int k = t * 16 + ((l >> 5) << 3) + i;
    int q = k >> 6, kk = k & 63;
    const float* Ws = (q & 1) ? sWr : sWl;
    Wfrag[id] = f2b(Ws[((2 * g + (q >> 1)) * 64 + kk) * 64 + d]);
  } else if (id < 65792) {                           // biasv[mt*32 + m32]
    int c = id - 65536;
    int mt = c >> 5, m32 = c & 31;
    int g = m32 & 3, d = mt * 8 + (m32 >> 2);
    biasv[c] = sbl[(2 * g) * 64 + d] + sbl[(2 * g + 1) * 64 + d] + gb[g * 64 + d];
  } else {                                           // Bdec [nt][96 t][lane][8]
    int p = id - 65792;                              // < 147456
    int i = p & 7, l = (p >> 3) & 63;
    int rem = p >> 9;                                // nt*96 + t
    int nt = rem / 96, t = rem - nt * 96;
    int e = nt * 32 + (l & 31);
    int k = t * 16 + ((l >> 5) << 3) + i;
    Bdec[p] = (e < 72) ? f2b(dW[k * 72 + e]) : (unsigned short)0;
  }
}

// ---------------------------------------------------------------------------
// mono: all 24 cells for 4 batch elements per block.
// ---------------------------------------------------------------------------
__global__ __launch_bounds__(512, 2) void mono5_kernel(
    const float* __restrict__ src, const float* __restrict__ tgt,
    const float* __restrict__ encW, const float* __restrict__ encb,
    const float* __restrict__ gw,
    const unsigned short* __restrict__ Wfrag,
    const float* __restrict__ biasv,
    unsigned short* __restrict__ obuf)
{
  __shared__ __align__(16) unsigned short Bf[3 * 16 * 64 * 8];  // 48 KB v-frags
  __shared__ __align__(16) unsigned short xs[96 * 64];          // 12 KB (swizzled)
  __shared__ __align__(16) unsigned short hs[96 * 64];          // 12 KB (swizzled)

  const int tid = threadIdx.x;
  const int n4 = blockIdx.x * 4;
  const int w = tid >> 6, l = tid & 63;      // wave = M-tile mt
  const int l31 = l & 31, hi = l >> 5;

  // ---- persistent W: 1 M-tile x 16 k-steps = 64 VGPR ---------------------
  bf16x8 W[16];
  {
    const bf16x8* p0 = reinterpret_cast<const bf16x8*>(Wfrag) + (w * 16) * 64 + l;
    #pragma unroll
    for (int t = 0; t < 16; ++t) W[t] = p0[t * 64];
  }
  // ---- bias (bf16-packed per acc-reg pair) -------------------------------
  unsigned bias_u[8];
  #pragma unroll
  for (int p = 0; p < 8; ++p) {
    int r0 = 2 * p, r1 = 2 * p + 1;
    int m0 = (r0 & 3) + 8 * (r0 >> 2) + 4 * hi;
    int m1 = (r1 & 3) + 8 * (r1 >> 2) + 4 * hi;
    bias_u[p] = pk2(biasv[w * 32 + m0], biasv[w * 32 + m1]);
  }
  // ---- gate_w scalars: d7 = 2u+hi, d = w*8 + d7 --------------------------
  float gwv[12];
  #pragma unroll
  for (int g = 0; g < 3; ++g)
    #pragma unroll
    for (int u = 0; u < 4; ++u)
      gwv[g * 4 + u] = gw[g * 64 + w * 8 + 2 * u + hi];

  float creg[12];                            // c-state: [nt][u]
  #pragma unroll
  for (int i = 0; i < 12; ++i) creg[i] = 0.0f;

  // zero h state
  for (int i = tid; i < 3072; i += 512) reinterpret_cast<unsigned*>(hs)[i] = 0u;

  auto enc_to_xs = [&](const float* base, int stride) {
    #pragma unroll
    for (int ii = 0; ii < 12; ++ii) {
      int idx = tid + ii * 512;                 // < 6144
      int ns = idx / 1536;
      int r2 = idx - ns * 1536;
      int jj = r2 >> 6, dd = r2 & 63;
      const float* f = base + (size_t)ns * stride + jj * 3;
      float v = encb[dd] + f[0] * encW[dd] + f[1] * encW[64 + dd] + f[2] * encW[128 + dd];
      int row = ns * 24 + jj;
      xs[row * 64 + (((dd >> 3) ^ (row & 7)) << 3) + (dd & 7)] = f2b(fmaxf(v, 0.0f));
    }
  };

  enc_to_xs(src + ((size_t)n4 * 16 + 4) * 72, 16 * 72);   // warm-up frame 4
  __syncthreads();

  #pragma unroll 1
  for (int step = 0; step < 24; ++step) {
    if (step == 12) {                          // decode init: re-encode tgt[:,0]
      enc_to_xs(tgt + (size_t)n4 * 12 * 72, 12 * 72);
      __syncthreads();
    }

    // ---- v-build: B-fragments [nt][t][lane][8] ---------------------------
    // Mrow fastest across lanes -> conflict-free ds_write_b128.
    #pragma unroll
    for (int it = 0; it < 3; ++it) {           // agg sections q0 (x), q2 (h)
      int job = tid + it * 512;                // < 1536
      int sec = (job >= 768) ? 1 : 0;
      int rem = job - sec * 768;
      int u8 = rem >> 8, r8 = rem & 255;
      int Mrow = u8 * 32 + (r8 & 31), ch = r8 >> 5;
      const unsigned short* sb = sec ? hs : xs;
      int ns = (Mrow * 2731) >> 16;
      int jj = Mrow - ns * 24;
      float s0 = 0, s1 = 0, s2 = 0, s3 = 0, s4 = 0, s5 = 0, s6 = 0, s7 = 0;
      #pragma unroll
      for (int m = 0; m < 5; ++m) {
        int nb = c_nbr[jj][m];
        if (nb >= 0) {
          int nr = ns * 24 + nb;
          uint4 u = *reinterpret_cast<const uint4*>(sb + nr * 64 + ((ch ^ (nr & 7)) << 3));
          s0 += b2f_lo(u.x); s1 += b2f_hi(u.x);
          s2 += b2f_lo(u.y); s3 += b2f_hi(u.y);
          s4 += b2f_lo(u.z); s5 += b2f_hi(u.z);
          s6 += b2f_lo(u.w); s7 += b2f_hi(u.w);
        }
      }
      float sc = c_invdeg[jj];
      uint4 o;
      o.x = pk2(s0 * sc, s1 * sc); o.y = pk2(s2 * sc, s3 * sc);
      o.z = pk2(s4 * sc, s5 * sc); o.w = pk2(s6 * sc, s7 * sc);
      int kb = sec * 128 + ch * 8;
      int t = kb >> 4, h2 = ch & 1;
      *reinterpret_cast<uint4*>(Bf + ((((Mrow >> 5) * 16 + t) * 64) + (Mrow & 31) + (h2 << 5)) * 8) = o;
    }
    #pragma unroll
    for (int it = 0; it < 3; ++it) {           // copy sections q1 (x), q3 (h)
      int job = tid + it * 512;
      int sec = (job >= 768) ? 1 : 0;
      int rem = job - sec * 768;
      int u8 = rem >> 8, r8 = rem & 255;
      int Mrow = u8 * 32 + (r8 & 31), ch = r8 >> 5;
      const unsigned short* sb = sec ? hs : xs;
      uint4 u = *reinterpret_cast<const uint4*>(sb + Mrow * 64 + ((ch ^ (Mrow & 7)) << 3));
      int kb = 64 + sec * 128 + ch * 8;
      int t = kb >> 4, h2 = ch & 1;
      *reinterpret_cast<uint4*>(Bf + ((((Mrow >> 5) * 16 + t) * 64) + (Mrow & 31) + (h2 << 5)) * 8) = u;
    }
    __syncthreads();

    // ---- GEMM: 48 MFMA (3 independent acc chains) ------------------------
    f32x16 a0, a1, a2;
    #pragma unroll
    for (int p = 0; p < 8; ++p) {
      float blo = b2f_lo(bias_u[p]), bhi = b2f_hi(bias_u[p]);
      a0[2 * p] = blo; a0[2 * p + 1] = bhi;
      a1[2 * p] = blo; a1[2 * p + 1] = bhi;
      a2[2 * p] = blo; a2[2 * p + 1] = bhi;
    }
    #pragma unroll
    for (int t = 0; t < 16; ++t) {
      bf16x8 v0 = *reinterpret_cast<const bf16x8*>(Bf + ((t) * 64 + l) * 8);
      bf16x8 v1 = *reinterpret_cast<const bf16x8*>(Bf + ((16 + t) * 64 + l) * 8);
      bf16x8 v2 = *reinterpret_cast<const bf16x8*>(Bf + ((32 + t) * 64 + l) * 8);
      a0 = __builtin_amdgcn_mfma_f32_32x32x16_bf16(W[t], v0, a0, 0, 0, 0);
      a1 = __builtin_amdgcn_mfma_f32_32x32x16_bf16(W[t], v1, a1, 0, 0, 0);
      a2 = __builtin_amdgcn_mfma_f32_32x32x16_bf16(W[t], v2, a2, 0, 0, 0);
    }

    // ---- lane-local epilogue: gates, c/h update, publish x=O, h ----------
#define EPI(NT, A)                                                             \
    {                                                                          \
      int row = (NT) * 32 + l31;                                               \
      int ns = (row * 2731) >> 16;                                             \
      int jj = row - ns * 24;                                                  \
      _Pragma("unroll")                                                        \
      for (int u = 0; u < 4; ++u) {                                            \
        float cv = creg[(NT) * 4 + u];                                         \
        float I = sigm_(A[4 * u + 0] + gwv[u] * cv);                           \
        float F = sigm_(A[4 * u + 1] + gwv[4 + u] * cv);                       \
        float T = tanh_(A[4 * u + 2]);                                         \
        float cn = F * cv + I * T;                                             \
        float O = sigm_(A[4 * u + 3] + gwv[8 + u] * cn);                       \
        float h = O * tanh_(cn);                                               \
        creg[(NT) * 4 + u] = cn;                                               \
        int d7 = 2 * u + hi;                                                   \
        int off = row * 64 + ((w ^ (row & 7)) << 3) + d7;                      \
        xs[off] = f2b(O);                                                      \
        hs[off] = f2b(h);                                                      \
        if (step >= 12)                                                        \
          obuf[((size_t)((n4 + ns) * 12 + (step - 12))) * 1536 + jj * 64 + w * 8 + d7] = f2b(O); \
      }                                                                        \
    }
    EPI(0, a0)
    EPI(1, a1)
    EPI(2, a2)
#undef EPI
    __syncthreads();
  }
}

// ---------------------------------------------------------------------------
// dec: out[row][e] = O[row,:] . decW[:,e] + db[e]; rows = n*12+ts.
// block: 32 rows, 4 waves K-split (384 each), 3 col-tiles, LDS reduce.
// ---------------------------------------------------------------------------
__global__ __launch_bounds__(256) void dec3_kernel(
    const unsigned short* __restrict__ obuf,
    const unsigned short* __restrict__ Bdec,
    const float* __restrict__ db,
    float* __restrict__ out)
{
  __shared__ float part[4 * 3 * 64 * 16];    // 48 KB
  const int tid = threadIdx.x;
  const int w = tid >> 6, l = tid & 63;
  const int l31 = l & 31, hi = l >> 5;
  const int r0 = blockIdx.x * 32;

  f32x16 a0, a1, a2;
  #pragma unroll
  for (int r = 0; r < 16; ++r) { a0[r] = 0.f; a1[r] = 0.f; a2[r] = 0.f; }

  const unsigned short* Ap = obuf + (size_t)(r0 + l31) * 1536 + hi * 8;
  #pragma unroll 4
  for (int tt = 0; tt < 24; ++tt) {
    int kt = w * 24 + tt;
    bf16x8 av = *reinterpret_cast<const bf16x8*>(Ap + kt * 16);
    bf16x8 b0 = *reinterpret_cast<const bf16x8*>(Bdec + ((0 * 96 + kt) * 64 + l) * 8);
    bf16x8 b1 = *reinterpret_cast<const bf16x8*>(Bdec + ((1 * 96 + kt) * 64 + l) * 8);
    bf16x8 b2 = *reinterpret_cast<const bf16x8*>(Bdec + ((2 * 96 + kt) * 64 + l) * 8);
    a0 = __builtin_amdgcn_mfma_f32_32x32x16_bf16(av, b0, a0, 0, 0, 0);
    a1 = __builtin_amdgcn_mfma_f32_32x32x16_bf16(av, b1, a1, 0, 0, 0);
    a2 = __builtin_amdgcn_mfma_f32_32x32x16_bf16(av, b2, a2, 0, 0, 0);
  }
  #pragma unroll
  for (int r = 0; r < 16; ++r) {
    part[((w * 3 + 0) * 64 + l) * 16 + r] = a0[r];
    part[((w * 3 + 1) * 64 + l) * 16 + r] = a1[r];
    part[((w * 3 + 2) * 64 + l) * 16 + r] = a2[r];
  }
  __syncthreads();

  // reduce 4 K-partials; thread -> (row = tid>>3, e = (tid&7)*12 + 0..11)
  int row = tid >> 3;
  int hi2 = (row >> 2) & 1;
  int rr = 4 * (row >> 3) + (row & 3);
  #pragma unroll
  for (int ei = 0; ei < 12; ++ei) {
    int e = (tid & 7) * 12 + ei;
    if (e < 72) {
      int nt = e >> 5, e32 = e & 31;
      float s = db[e];
      #pragma unroll
      for (int w2 = 0; w2 < 4; ++w2)
        s += part[((w2 * 3 + nt) * 64 + e32 + 32 * hi2) * 16 + rr];
      out[(size_t)(r0 + row) * 72 + e] = s;
    }
  }
}

// ---------------------------------------------------------------------------
extern "C" void kernel_launch(void* const* d_in, const int* in_sizes, int n_in,
                              void* d_out, int out_size, void* d_ws, size_t ws_size,
                              hipStream_t stream) {
  const float* src  = (const float*)d_in[0];   // [1024,16,72]
  const float* tgt  = (const float*)d_in[1];   // [1024,12,72]
  const float* encW = (const float*)d_in[2];   // [3,64]
  const float* encb = (const float*)d_in[3];   // [64]
  const float* sWl  = (const float*)d_in[4];   // [8,64,64]
  const float* sbl  = (const float*)d_in[5];   // [8,64]
  const float* sWr  = (const float*)d_in[6];   // [8,64,64]
  const float* gw   = (const float*)d_in[7];   // [3,1,64]
  const float* gb   = (const float*)d_in[8];   // [4,1,64]
  const float* dW   = (const float*)d_in[9];   // [1536,72]
  const float* db   = (const float*)d_in[10];  // [72]
  float* out = (float*)d_out;

  unsigned short* obuf  = (unsigned short*)d_ws;        // 12288*1536 bf16
  unsigned short* Wfrag = obuf + (size_t)12288 * 1536;  // 65536 bf16
  unsigned short* Bdec  = Wfrag + 65536;                // 147456 bf16
  float*          biasv = (float*)(Bdec + 147456);      // 256 f32

  prep3_kernel<<<833, 256, 0, stream>>>(sWl, sbl, sWr, gb, dW, Wfrag, biasv, Bdec);
  mono5_kernel<<<256, 512, 0, stream>>>(src, tgt, encW, encb, gw, Wfrag, biasv, obuf);
  dec3_kernel<<<384, 256, 0, stream>>>(obuf, Bdec, db, out);
}